// Round 1
// baseline (313.250 us; speedup 1.0000x reference)
//
#include <hip/hip_runtime.h>
#include <math.h>

typedef unsigned int u32;
typedef unsigned long long u64;

#define HW    30720     // 96*320
#define W_    320
#define H_    96
#define B_    16
#define KTOP  100
#define NIMG  192       // 16*3 (hm) + 16*9 (hm_hp)

// ---------------------------------------------------------------------------
// Kernel 1: fused sigmoid + 3x3 NMS.
// Output per pixel: monotone-ordered u32 key = float bits of sigmoid(center)
// if the pixel is a 3x3 local max (raw-space max == sigmoid-space max by
// monotonicity), else 0 (sigmoid>0 always, so 0 is a safe "suppressed" mark).
// ---------------------------------------------------------------------------
__global__ __launch_bounds__(256) void nms_sig_kernel(
    const float* __restrict__ hm, const float* __restrict__ hm_hp,
    u32* __restrict__ Nk)
{
    int gid = blockIdx.x * 256 + threadIdx.x;
    if (gid >= NIMG * HW) return;
    int img = gid / HW;
    int pix = gid - img * HW;
    const float* base = (img < 48) ? (hm + (size_t)img * HW)
                                   : (hm_hp + (size_t)(img - 48) * HW);
    int y = pix / W_;
    int x = pix - y * W_;
    float c = base[pix];
    float m = c;
    int y0 = (y > 0) ? y - 1 : 0, y1 = (y < H_ - 1) ? y + 1 : H_ - 1;
    int x0 = (x > 0) ? x - 1 : 0, x1 = (x < W_ - 1) ? x + 1 : W_ - 1;
    for (int yy = y0; yy <= y1; ++yy)
        for (int xx = x0; xx <= x1; ++xx)
            m = fmaxf(m, base[yy * W_ + xx]);
    u32 key = 0u;
    if (c == m) {
        float s = 1.0f / (1.0f + expf(-c));
        key = __float_as_uint(s);   // s in (0,1): positive float -> bits are monotone
    }
    Nk[gid] = key;
}

// ---------------------------------------------------------------------------
// Kernel 2: exact per-row (per b,c image) top-100 with lax.top_k semantics
// (value desc, index asc). Two-round 12-bit radix select on the key bits to
// find a 24-bit-prefix cut containing >= 100 candidates, compact them to LDS,
// bitonic-sort packed (key, ~idx) keys descending, emit first 100.
// ---------------------------------------------------------------------------
__global__ __launch_bounds__(256) void topk_kernel(
    const u32* __restrict__ Nk, u32* __restrict__ tkKey, u32* __restrict__ tkIdx)
{
    const int row = blockIdx.x;
    const int tid = threadIdx.x;
    const u32* base = Nk + (size_t)row * HW;

    __shared__ u32 hist[4096];
    __shared__ u64 cand[2048];
    __shared__ u32 chunkv[256];
    __shared__ u32 cnt;
    __shared__ u32 sel[3];   // b1, G1, b2

    // ---- round 1: histogram of key[31:20] ----
    for (int i = tid; i < 4096; i += 256) hist[i] = 0;
    __syncthreads();
    for (int i = tid; i < HW; i += 256) {
        u32 k = base[i];
        if (k) atomicAdd(&hist[k >> 20], 1u);
    }
    __syncthreads();
    { u32 s = 0; int c0 = tid * 16;
      for (int q = 0; q < 16; ++q) s += hist[c0 + q];
      chunkv[tid] = s; }
    __syncthreads();
    if (tid == 0) {
        u32 run = 0; u32 b1 = 0, G1 = 0;
        for (int c = 255; c >= 0; --c) {
            u32 s = chunkv[c];
            if (run + s >= KTOP) {
                for (int bin = c * 16 + 15; bin >= c * 16; --bin) {
                    u32 h = hist[bin];
                    if (run + h >= KTOP) { b1 = (u32)bin; G1 = run; break; }
                    run += h;
                }
                break;
            }
            run += s;
        }
        sel[0] = b1; sel[1] = G1;
    }
    __syncthreads();
    const u32 b1 = sel[0], G1 = sel[1];

    // ---- round 2: refine within bin b1 on key[19:8] ----
    for (int i = tid; i < 4096; i += 256) hist[i] = 0;
    __syncthreads();
    for (int i = tid; i < HW; i += 256) {
        u32 k = base[i];
        if (k && (k >> 20) == b1) atomicAdd(&hist[(k >> 8) & 0xFFFu], 1u);
    }
    __syncthreads();
    { u32 s = 0; int c0 = tid * 16;
      for (int q = 0; q < 16; ++q) s += hist[c0 + q];
      chunkv[tid] = s; }
    __syncthreads();
    if (tid == 0) {
        u32 K2 = KTOP - G1;   // >= 1
        u32 run = 0; u32 b2 = 0;
        for (int c = 255; c >= 0; --c) {
            u32 s = chunkv[c];
            if (run + s >= K2) {
                for (int bin = c * 16 + 15; bin >= c * 16; --bin) {
                    u32 h = hist[bin];
                    if (run + h >= K2) { b2 = (u32)bin; break; }
                    run += h;
                }
                break;
            }
            run += s;
        }
        sel[2] = b2;
        cnt = 0;
    }
    __syncthreads();
    const u32 cut24 = (b1 << 12) | sel[2];

    // ---- round 3: compact qualifying candidates (24-bit prefix >= cut) ----
    for (int i = tid; i < HW; i += 256) {
        u32 k = base[i];
        if (k && (k >> 8) >= cut24) {
            u32 p = atomicAdd(&cnt, 1u);
            if (p < 2048) cand[p] = ((u64)k << 32) | (u32)(~(u32)i);
        }
    }
    __syncthreads();
    u32 n = cnt; if (n > 2048) n = 2048;
    u32 npow = 128; while (npow < n) npow <<= 1;
    for (u32 i = n + tid; i < npow; i += 256) cand[i] = 0ull;
    __syncthreads();

    // ---- bitonic sort descending (key desc, idx asc via ~idx) ----
    for (u32 ks = 2; ks <= npow; ks <<= 1) {
        for (u32 j = ks >> 1; j > 0; j >>= 1) {
            for (u32 i = tid; i < npow; i += 256) {
                u32 ix = i ^ j;
                if (ix > i) {
                    u64 a = cand[i], b = cand[ix];
                    bool sw = ((i & ks) == 0) ? (a < b) : (a > b);
                    if (sw) { cand[i] = b; cand[ix] = a; }
                }
            }
            __syncthreads();
        }
    }
    if (tid < KTOP) {
        u64 v = cand[tid];
        tkKey[row * KTOP + tid] = (u32)(v >> 32);
        tkIdx[row * KTOP + tid] = ~(u32)v;
    }
}

// ---------------------------------------------------------------------------
// Kernel 3: per-batch decode. Second-stage top-100 of 300 hm candidates,
// gathers, hm_hp keypoint candidate prep, min-dist matching, output compose.
// One block per batch element.
// ---------------------------------------------------------------------------
__global__ __launch_bounds__(256) void decode_kernel(
    const u32* __restrict__ tkKey, const u32* __restrict__ tkIdx,
    const float* __restrict__ wh,   const float* __restrict__ hps,
    const float* __restrict__ dimp, const float* __restrict__ rot,
    const float* __restrict__ prob, const float* __restrict__ reg,
    const float* __restrict__ hpo,  float* __restrict__ det)
{
    const int b = blockIdx.x;
    const int tid = threadIdx.x;

    __shared__ u64 arr[512];
    __shared__ float la[KTOP], ta[KTOP], ra[KTOP], ba2[KTOP];
    __shared__ float kx[9][KTOP], ky[9][KTOP];
    __shared__ float hsv[9][KTOP], hxv[9][KTOP], hyv[9][KTOP];

    // ---- second-stage topk over the 3 channels' 100 each ----
    for (int i = tid; i < 512; i += 256) {
        u64 v = 0ull;
        if (i < 300) {
            int c = i / 100, r = i - c * 100;
            u32 key = tkKey[(b * 3 + c) * KTOP + r];
            // flattened position i = c*K + rank -> stable tie-break like lax.top_k
            v = ((u64)key << 32) | (u32)(~(u32)i);
        }
        arr[i] = v;
    }
    __syncthreads();
    for (u32 ks = 2; ks <= 512; ks <<= 1) {
        for (u32 j = ks >> 1; j > 0; j >>= 1) {
            for (u32 i = tid; i < 512; i += 256) {
                u32 ix = i ^ j;
                if (ix > i) {
                    u64 a = arr[i], bb = arr[ix];
                    bool sw = ((i & ks) == 0) ? (a < bb) : (a > bb);
                    if (sw) { arr[i] = bb; arr[ix] = a; }
                }
            }
            __syncthreads();
        }
    }

    // ---- hm_hp candidates: score/x/y with offset + validity masking ----
    for (int t2 = tid; t2 < 900; t2 += 256) {
        int j = t2 / 100, r = t2 - j * 100;
        int row = 48 + b * 9 + j;
        u32 key = tkKey[row * KTOP + r];
        u32 idx = tkIdx[row * KTOP + r];
        if (idx > HW - 1) idx = HW - 1;          // safety (pad entries)
        float s = __uint_as_float(key);
        int yy = (int)idx / W_, xx = (int)idx - yy * W_;
        float hx = (float)xx + hpo[((size_t)b * 2 + 0) * HW + idx];
        float hy = (float)yy + hpo[((size_t)b * 2 + 1) * HW + idx];
        bool valid = s > 0.1f;
        hsv[j][r] = valid ? s : -1.0f;
        hxv[j][r] = valid ? hx : -10000.0f;
        hyv[j][r] = valid ? hy : -10000.0f;
    }

    // ---- per-detection gathers + direct writes of non-kps fields ----
    if (tid < KTOP) {
        int k = tid;
        u64 v = arr[k];
        u32 pos = ~(u32)v;
        if (pos > 299u) pos = 299u;              // safety (pad entries)
        u32 key = (u32)(v >> 32);
        int c = (int)pos / 100, r = (int)pos - c * 100;
        u32 sid = tkIdx[(b * 3 + c) * KTOP + r];
        if (sid > HW - 1) sid = HW - 1;          // safety
        float score = __uint_as_float(key);
        int yy = (int)sid / W_, xx = (int)sid - yy * W_;
        float xs0 = (float)xx, ys0 = (float)yy;
        float r0 = reg[((size_t)b * 2 + 0) * HW + sid];
        float r1 = reg[((size_t)b * 2 + 1) * HW + sid];
        float xsv = xs0 + r0, ysv = ys0 + r1;
        float w0 = wh[((size_t)b * 2 + 0) * HW + sid];
        float w1 = wh[((size_t)b * 2 + 1) * HW + sid];
        float l  = xsv - w0 * 0.5f;   // product exact (x0.5) -> contraction-safe
        float t  = ysv - w1 * 0.5f;
        float rr = xsv + w0 * 0.5f;
        float bb = ysv + w1 * 0.5f;
        la[k] = l; ta[k] = t; ra[k] = rr; ba2[k] = bb;

        float* o = det + ((size_t)b * KTOP + k) * 45;
        o[0] = l * 4.0f; o[1] = t * 4.0f; o[2] = rr * 4.0f; o[3] = bb * 4.0f;
        o[4] = score;
        #pragma unroll
        for (int q = 0; q < 3; ++q)
            o[23 + q] = dimp[((size_t)b * 3 + q) * HW + sid];
        #pragma unroll
        for (int q = 0; q < 8; ++q)
            o[35 + q] = rot[((size_t)b * 8 + q) * HW + sid];
        o[43] = prob[(size_t)b * HW + sid];
        o[44] = (float)c;
        #pragma unroll
        for (int j = 0; j < 9; ++j) {
            kx[j][k] = hps[((size_t)b * 18 + 2 * j)     * HW + sid] + xs0;
            ky[j][k] = hps[((size_t)b * 18 + 2 * j + 1) * HW + sid] + ys0;
        }
    }
    __syncthreads();

    // ---- min-distance matching (argmin first-wins) + kps compose ----
    for (int p = tid; p < 900; p += 256) {
        int j = p / 100, k = p - j * 100;
        float qx = kx[j][k], qy = ky[j][k];
        float best = INFINITY; int bi = 0;
        for (int m = 0; m < 100; ++m) {
            float dx = qx - hxv[j][m];
            float dy = qy - hyv[j][m];
            // no fp-contract: match ref's (dx*dx) + (dy*dy), then sqrt
            float d2 = __fadd_rn(__fmul_rn(dx, dx), __fmul_rn(dy, dy));
            float d = __fsqrt_rn(d2);
            if (d < best) { best = d; bi = m; }
        }
        float ss = hsv[j][bi], hx = hxv[j][bi], hy = hyv[j][bi];
        float l = la[k], t = ta[k], rr = ra[k], bb = ba2[k];
        float th = __fmul_rn(fmaxf(__fsub_rn(bb, t), __fsub_rn(rr, l)), 0.3f);
        bool invalid = (hx < l) | (hx > rr) | (hy < t) | (hy > bb) |
                       (ss < 0.1f) | (best > th);
        float ox = invalid ? kx[j][k] : hx;
        float oy = invalid ? ky[j][k] : hy;
        float* o = det + ((size_t)b * KTOP + k) * 45;
        o[5 + 2 * j] = ox * 4.0f;
        o[6 + 2 * j] = oy * 4.0f;
        o[26 + j]    = ss;          // hm_score_sel regardless of invalid
    }
}

// ---------------------------------------------------------------------------
extern "C" void kernel_launch(void* const* d_in, const int* in_sizes, int n_in,
                              void* d_out, int out_size, void* d_ws, size_t ws_size,
                              hipStream_t stream) {
    const float* hm    = (const float*)d_in[0];
    const float* wh    = (const float*)d_in[1];
    const float* hps   = (const float*)d_in[2];
    const float* dimp  = (const float*)d_in[3];
    const float* rot   = (const float*)d_in[4];
    const float* prob  = (const float*)d_in[5];
    const float* reg   = (const float*)d_in[6];
    const float* hm_hp = (const float*)d_in[7];
    const float* hpo   = (const float*)d_in[8];
    float* det = (float*)d_out;

    u32* Nk    = (u32*)d_ws;                    // 192*30720 u32 = 23.6 MB
    u32* tkKey = Nk + (size_t)NIMG * HW;        // 192*100
    u32* tkIdx = tkKey + NIMG * KTOP;           // 192*100

    nms_sig_kernel<<<(NIMG * HW + 255) / 256, 256, 0, stream>>>(hm, hm_hp, Nk);
    topk_kernel<<<NIMG, 256, 0, stream>>>(Nk, tkKey, tkIdx);
    decode_kernel<<<B_, 256, 0, stream>>>(tkKey, tkIdx, wh, hps, dimp, rot,
                                          prob, reg, hpo, det);
}